// Round 7
// baseline (7012.255 us; speedup 1.0000x reference)
//
#include <hip/hip_runtime.h>
#include <cstdint>
#include <cstddef>

// =====================================================================
// RBM Gibbs sampling, bit-exact replication of JAX-on-CPU reference.
//
// ROUND 6: single change vs round 5 — h-GEMM uses Eigen kc-slab fold
// (KC=320): per element C=0; per slab: acc=0, += terms k-ascending
// (k=c*512+v, c-major); C+=acc at slab crossings. Empty slabs fold +0
// (no-op) so skip-scan fold-on-crossing is bit-identical to Eigen.
// WHY: round 5 moved the failure from Output 0 to Output 2 ONLY
// (h_given_v0, exactly 1 flip). Outputs 0/1 bit-exact => RNG stack,
// transcendentals, v-GEMM, keys, idx all verified. A single boundary
// flip (u within ~1e-8 of p) across 12.6M bernoulli draws is exactly
// the signature of a ulp-level REDUCTION-ORDER mismatch in the h-GEMM.
// Rounds 1-3's slab tests were void: ws_size in [11.5,28.6)MB => perm
// buffer was OOB in rounds 0-4 (round-4-vs-5 bit-identical semantics,
// different outcomes, proves it). Sentinels stayed silent => contract
// constants verified.
// Held fixed (verified by outputs 0/1 passing):
//  - threefry2x32 partitionable; fold-like split; seed(42)->(0,42).
//  - cephes-Horner exp, Pommier-Horner log (q1/q2 tail), no contract.
//  - sigmoid = 1/(1+exp(-x)) IEEE div; gumbel tiny-clamp; first-max
//    argmax; bernoulli u<p; v-GEMM K=256 single sequential chain.
// =====================================================================

#define B_DIM 16384
#define C_DIM 5
#define H_DIM 256
#define V_DIM 512
#define KC    320   // Eigen MT gebp kc (Zen5 48KB L1d: min(435,320)=320)

struct TFOut { uint32_t a, b; };

__host__ __device__ static inline TFOut tf2x32(uint32_t k0, uint32_t k1,
                                               uint32_t c0, uint32_t c1) {
  uint32_t ks2 = k0 ^ k1 ^ 0x1BD11BDAu;
  uint32_t x0 = c0 + k0, x1 = c1 + k1;
#define TF_R(r) { x0 += x1; x1 = (x1 << r) | (x1 >> (32 - r)); x1 ^= x0; }
  TF_R(13) TF_R(15) TF_R(26) TF_R(6)
  x0 += k1;  x1 += ks2 + 1u;
  TF_R(17) TF_R(29) TF_R(16) TF_R(24)
  x0 += ks2; x1 += k0 + 2u;
  TF_R(13) TF_R(15) TF_R(26) TF_R(6)
  x0 += k0;  x1 += k1 + 3u;
  TF_R(17) TF_R(29) TF_R(16) TF_R(24)
  x0 += k1;  x1 += ks2 + 4u;
  TF_R(13) TF_R(15) TF_R(26) TF_R(6)
  x0 += ks2; x1 += k0 + 5u;
#undef TF_R
  TFOut o; o.a = x0; o.b = x1; return o;
}

// partitionable random_bits, 32-bit width, element index i (< 2^32)
__device__ static inline uint32_t rng_bits(uint32_t k0, uint32_t k1, uint32_t i) {
  TFOut r = tf2x32(k0, k1, 0u, i);
  return r.a ^ r.b;
}

__device__ static inline float bits_to_unit_float(uint32_t bits) {
  return __uint_as_float((bits >> 9) | 0x3F800000u) - 1.0f;
}

// XLA GenerateVF32Exp replica (cephes Horner port), mul+add separate,
// NO contraction.
__device__ static float xla_exp(float x_in) {
#pragma clang fp contract(off)
  float x = fminf(x_in, 88.3762626647950f);
  x = fmaxf(x, -88.3762626647949f);
  float fx = floorf(x * 1.44269504088896341f + 0.5f);
  float tmp = fx * 0.693359375f;
  float z = fx * -2.12194440e-4f;
  x = x - tmp;
  x = x - z;
  z = x * x;
  float y = 1.9875691500e-4f;
  y = y * x + 1.3981999507e-3f;
  y = y * x + 8.3334519073e-3f;
  y = y * x + 4.1665795894e-2f;
  y = y * x + 1.6666665459e-1f;
  y = y * x + 5.0000001201e-1f;
  y = y * z + x;
  y = y + 1.0f;
  int n = (int)fx;
  y = y * __uint_as_float((uint32_t)(n + 127) << 23);
  return y;
}

// XLA GenerateVF32Log replica = Pommier/Eigen3.3 log_ps (Horner + tail:
// y+=e*q1; y-=0.5*z; x+=y; x+=e*q2). NO contraction.
__device__ static float xla_log(float x_in) {
#pragma clang fp contract(off)
  float xv = fmaxf(x_in, 1.17549435e-38f);      // min_norm_pos clamp
  uint32_t bits = __float_as_uint(xv);
  float e = (float)((int)(bits >> 23) - 126);
  float x = __uint_as_float((bits & 0x007FFFFFu) | 0x3F000000u);  // [0.5,1)
  bool m = (x < 0.707106781186547524f);
  float tmp = m ? x : 0.0f;
  x = x - 1.0f;
  e = e - (m ? 1.0f : 0.0f);
  x = x + tmp;
  float z = x * x;
  float y = 7.0376836292e-2f;
  y = y * x + -1.1514610310e-1f;
  y = y * x + 1.1676998740e-1f;
  y = y * x + -1.2420140846e-1f;
  y = y * x + 1.4249322787e-1f;
  y = y * x + -1.6668057665e-1f;
  y = y * x + 2.0000714765e-1f;
  y = y * x + -2.4999993993e-1f;
  y = y * x + 3.3333331174e-1f;
  y = y * x;
  y = y * z;
  float t1 = e * -2.12194440e-4f;
  y = y + t1;
  float t2 = z * 0.5f;
  y = y - t2;
  x = x + y;
  float t3 = e * 0.693359375f;
  x = x + t3;
  return x;
}

// ---------------- kernels ----------------

__global__ void k_sentinel(float* out, float d) {
  out[0] = d;
}

// v0 one-hot (B,C,V) -> idx (B,V) u8
__global__ __launch_bounds__(256) void k_idx(const float* __restrict__ v0,
                                             uint8_t* __restrict__ idx) {
  int t = blockIdx.x * 256 + threadIdx.x;          // b*V + v
  int b = t >> 9, v = t & 511;
  const float* p = v0 + (size_t)b * (C_DIM * V_DIM) + v;
  int cf = 0;
#pragma unroll
  for (int c = 0; c < C_DIM; ++c)
    if (p[c * V_DIM] > 0.5f) cf = c;
  idx[t] = (uint8_t)cf;
}

// W (c,h,v) -> Wt (c,v,h)
__global__ __launch_bounds__(256) void k_wt(const float* __restrict__ W,
                                            float* __restrict__ Wt) {
  int t = blockIdx.x * 256 + threadIdx.x;          // (c, v, h)
  int h = t & 255; int rest = t >> 8; int v = rest & 511; int c = rest >> 9;
  Wt[t] = W[((size_t)c * H_DIM + h) * V_DIM + v];
}

// h = bernoulli(sigmoid(kc-slab-folded k-ascending sum + c1))
__global__ __launch_bounds__(256) void k_sample_h(
    const float* __restrict__ Wt, const float* __restrict__ c1,
    const uint8_t* __restrict__ idx,
    float* __restrict__ out_h, uint32_t* __restrict__ out_mask,
    uint32_t key0, uint32_t key1) {
  __shared__ uint8_t sidx[V_DIM];
  int b = blockIdx.x;
  int h = threadIdx.x;
  if (h < 128)
    ((uint32_t*)sidx)[h] = ((const uint32_t*)(idx + (size_t)b * V_DIM))[h];
  __syncthreads();

  float total = 0.0f, psum = 0.0f;
  int panel = 0;
  for (int c = 0; c < C_DIM; ++c) {
    const float* Wc = Wt + ((size_t)c * V_DIM) * H_DIM + h;
    int kbase = c * V_DIM;
    for (int v = 0; v < V_DIM; ++v) {
      if (sidx[v] == (uint8_t)c) {
        int pnl = (kbase + v) / KC;
        if (pnl != panel) { total += psum; psum = 0.0f; panel = pnl; }
        psum += Wc[(size_t)v * H_DIM];
      }
    }
  }
  total += psum;

  float t = total + c1[h];
  float p = 1.0f / (1.0f + xla_exp(-t));   // IEEE div, logistic exp form

  uint32_t i = (uint32_t)(b * H_DIM + h);
  float u = bits_to_unit_float(rng_bits(key0, key1, i));
  bool hb = (u < p);
  if (out_h) out_h[(size_t)b * H_DIM + h] = hb ? 1.0f : 0.0f;

  unsigned long long m = __ballot(hb);
  int wave = threadIdx.x >> 6;
  if ((threadIdx.x & 63) == 0) {
    out_mask[(size_t)b * 8 + wave * 2 + 0] = (uint32_t)(m & 0xFFFFFFFFull);
    out_mask[(size_t)b * 8 + wave * 2 + 1] = (uint32_t)(m >> 32);
  }
}

// v = categorical over c of (sum_h W[c,h,v]*hbit + b2 + gumbel); 8 b's/block
__global__ __launch_bounds__(512) void k_sample_v(
    const float* __restrict__ W, const float* __restrict__ b2,
    const uint32_t* __restrict__ mask, uint8_t* __restrict__ idx_out,
    uint32_t key0, uint32_t key1) {
  __shared__ uint32_t sm[8][8];
  int v = threadIdx.x;
  int b0 = blockIdx.x * 8;
  if (threadIdx.x < 64)
    sm[threadIdx.x >> 3][threadIdx.x & 7] = mask[(size_t)b0 * 8 + threadIdx.x];
  __syncthreads();

  float best[8];
  int bc[8];
#pragma unroll
  for (int g = 0; g < 8; ++g) { best[g] = 0.0f; bc[g] = 0; }

  for (int c = 0; c < C_DIM; ++c) {
    float acc[8] = {0.f,0.f,0.f,0.f,0.f,0.f,0.f,0.f};
    const float* Wc = W + (size_t)c * (H_DIM * V_DIM) + v;
    for (int word = 0; word < 8; ++word) {
      uint32_t mw[8];
#pragma unroll
      for (int g = 0; g < 8; ++g) mw[g] = sm[g][word];
      for (int bit = 0; bit < 32; ++bit) {
        float w = Wc[(size_t)(word * 32 + bit) * V_DIM];
#pragma unroll
        for (int g = 0; g < 8; ++g)
          acc[g] += ((mw[g] >> bit) & 1u) ? w : 0.0f;  // exact skip/add
      }
    }
    float bias = b2[(size_t)c * V_DIM + v];
#pragma unroll
    for (int g = 0; g < 8; ++g) {
      float logit = acc[g] + bias;
      uint32_t i = (uint32_t)((b0 + g) * (C_DIM * V_DIM) + c * V_DIM + v);
      float uf = bits_to_unit_float(rng_bits(key0, key1, i));
      if (uf == 0.0f) uf = 1.17549435e-38f;            // u + tiny semantics
      float gum = -xla_log(-xla_log(uf));
      float z = gum + logit;
      if (c == 0 || z > best[g]) { best[g] = z; bc[g] = c; }
    }
  }
#pragma unroll
  for (int g = 0; g < 8; ++g)
    idx_out[(size_t)(b0 + g) * V_DIM + v] = (uint8_t)bc[g];
}

// idx -> one-hot f32 (B,C,V)
__global__ __launch_bounds__(256) void k_onehot(const uint8_t* __restrict__ idx,
                                                float* __restrict__ out) {
  int t = blockIdx.x * 256 + threadIdx.x;     // b*C*V + c*V + v
  int v = t & 511; int rest = t >> 9; int c = rest % C_DIM; int b = rest / C_DIM;
  out[t] = (idx[(size_t)b * V_DIM + v] == c) ? 1.0f : 0.0f;
}

// ---------------- launch ----------------

extern "C" void kernel_launch(void* const* d_in, const int* in_sizes, int n_in,
                              void* d_out, int out_size, void* d_ws, size_t ws_size,
                              hipStream_t stream) {
  float* out = (float*)d_out;

  // ---- structural sentinels (verified silent in round 5) ----
  const size_t WS_NEED = 2621440ull + 8388608ull + 524288ull;  // 11,534,336 B
  float D = 0.0f;
  if (n_in < 4)                       D = 910.0f + (float)n_in;
  else if (in_sizes[0] != 41943040)   D = 920.0f;
  else if (in_sizes[1] != 655360)     D = 921.0f;
  else if (in_sizes[2] != 2560)       D = 922.0f;
  else if (in_sizes[3] != 256)        D = 923.0f;
  else if (out_size != 50331648)      D = 930.0f + (float)out_size * 1e-6f;
  else if (ws_size < WS_NEED)         D = 100.0f + (float)(ws_size >> 20);
  if (D != 0.0f) {
    hipLaunchKernelGGL(k_sentinel, dim3(1), dim3(1), 0, stream, out, D);
    return;
  }

  const float* v0 = (const float*)d_in[0];
  const float* W  = (const float*)d_in[1];
  const float* b2 = (const float*)d_in[2];   // (C,V)
  const float* c1 = (const float*)d_in[3];   // (H)

  float* out_v  = out;                                         // B*C*V
  float* out_h  = out + (size_t)B_DIM * C_DIM * V_DIM;         // B*H (final h)
  float* out_h0 = out_h + (size_t)B_DIM * H_DIM;               // B*H (h|v0)

  char* ws = (char*)d_ws;
  float*    Wt   = (float*)(ws);                    // 2,621,440 B
  uint8_t*  idx  = (uint8_t*)(ws + 2621440);        // 8,388,608 B
  uint32_t* mask = (uint32_t*)(ws + 11010048);      //   524,288 B

  // partitionable (fold-like) split of key(42) into 5 subkeys
  uint32_t keys[5][2];
  for (int i = 0; i < 5; ++i) {
    TFOut r = tf2x32(0u, 42u, 0u, (uint32_t)i);
    keys[i][0] = r.a; keys[i][1] = r.b;
  }

  hipLaunchKernelGGL(k_wt,  dim3(2560),  dim3(256), 0, stream, W, Wt);
  hipLaunchKernelGGL(k_idx, dim3(32768), dim3(256), 0, stream, v0, idx);

  // h0 = sample_h(keys[0], v0) -> h_given_v0 output + mask
  hipLaunchKernelGGL(k_sample_h, dim3(B_DIM), dim3(256), 0, stream,
                     Wt, c1, idx, out_h0, mask, keys[0][0], keys[0][1]);
  // iter 0: v = sample_v(keys[1], h0); h1 = sample_h(keys[2], v)
  hipLaunchKernelGGL(k_sample_v, dim3(B_DIM / 8), dim3(512), 0, stream,
                     W, b2, mask, idx, keys[1][0], keys[1][1]);
  hipLaunchKernelGGL(k_sample_h, dim3(B_DIM), dim3(256), 0, stream,
                     Wt, c1, idx, (float*)nullptr, mask, keys[2][0], keys[2][1]);
  // iter 1: v = sample_v(keys[3], h1); h2 = sample_h(keys[4], v)
  hipLaunchKernelGGL(k_sample_v, dim3(B_DIM / 8), dim3(512), 0, stream,
                     W, b2, mask, idx, keys[3][0], keys[3][1]);
  hipLaunchKernelGGL(k_sample_h, dim3(B_DIM), dim3(256), 0, stream,
                     Wt, c1, idx, out_h, mask, keys[4][0], keys[4][1]);
  // final v one-hot output
  hipLaunchKernelGGL(k_onehot, dim3(163840), dim3(256), 0, stream, idx, out_v);
}

// Round 8
// 3445.061 us; speedup vs baseline: 2.0355x; 2.0355x over previous
//
#include <hip/hip_runtime.h>
#include <cstdint>
#include <cstddef>

// =====================================================================
// RBM Gibbs sampling, bit-exact replication of JAX-on-CPU reference.
// ROUND 7 (perf): k_sample_h rewritten — in-LDS ballot counting-sort
// compaction (ascending k = c*512+v, identical order to round 6's
// skip-scan) + binary-searched kc=320 panel boundaries; main loop now
// 512 compact iterations (broadcast LDS offset + coalesced L2 load +
// dependent add, 4x unroll) instead of a 2560-cell redundant scan.
// Semantics FROZEN from round 6 (passed, absmax=0):
//  - threefry2x32 partitionable; fold-like split; seed(42)->(0,42).
//  - cephes-Horner exp, Pommier-Horner log (q1/q2 tail), no contract.
//  - sigmoid = 1/(1+exp(-x)) IEEE div; gumbel tiny-clamp; first-max
//    argmax; bernoulli u<p; v-GEMM K=256 single sequential chain.
//  - h-GEMM: Eigen gebp kc=320 slab fold, k ascending (c-major).
//    Empty slab folds +0.0 (exact; acc never -0). Zero terms skipped
//    (exact no-ops).
// =====================================================================

#define B_DIM 16384
#define C_DIM 5
#define H_DIM 256
#define V_DIM 512
#define KC    320   // Eigen MT gebp kc (Zen5 48KB L1d: min(435,320)=320)

struct TFOut { uint32_t a, b; };

__host__ __device__ static inline TFOut tf2x32(uint32_t k0, uint32_t k1,
                                               uint32_t c0, uint32_t c1) {
  uint32_t ks2 = k0 ^ k1 ^ 0x1BD11BDAu;
  uint32_t x0 = c0 + k0, x1 = c1 + k1;
#define TF_R(r) { x0 += x1; x1 = (x1 << r) | (x1 >> (32 - r)); x1 ^= x0; }
  TF_R(13) TF_R(15) TF_R(26) TF_R(6)
  x0 += k1;  x1 += ks2 + 1u;
  TF_R(17) TF_R(29) TF_R(16) TF_R(24)
  x0 += ks2; x1 += k0 + 2u;
  TF_R(13) TF_R(15) TF_R(26) TF_R(6)
  x0 += k0;  x1 += k1 + 3u;
  TF_R(17) TF_R(29) TF_R(16) TF_R(24)
  x0 += k1;  x1 += ks2 + 4u;
  TF_R(13) TF_R(15) TF_R(26) TF_R(6)
  x0 += ks2; x1 += k0 + 5u;
#undef TF_R
  TFOut o; o.a = x0; o.b = x1; return o;
}

// partitionable random_bits, 32-bit width, element index i (< 2^32)
__device__ static inline uint32_t rng_bits(uint32_t k0, uint32_t k1, uint32_t i) {
  TFOut r = tf2x32(k0, k1, 0u, i);
  return r.a ^ r.b;
}

__device__ static inline float bits_to_unit_float(uint32_t bits) {
  return __uint_as_float((bits >> 9) | 0x3F800000u) - 1.0f;
}

// XLA GenerateVF32Exp replica (cephes Horner port), mul+add separate,
// NO contraction.
__device__ static float xla_exp(float x_in) {
#pragma clang fp contract(off)
  float x = fminf(x_in, 88.3762626647950f);
  x = fmaxf(x, -88.3762626647949f);
  float fx = floorf(x * 1.44269504088896341f + 0.5f);
  float tmp = fx * 0.693359375f;
  float z = fx * -2.12194440e-4f;
  x = x - tmp;
  x = x - z;
  z = x * x;
  float y = 1.9875691500e-4f;
  y = y * x + 1.3981999507e-3f;
  y = y * x + 8.3334519073e-3f;
  y = y * x + 4.1665795894e-2f;
  y = y * x + 1.6666665459e-1f;
  y = y * x + 5.0000001201e-1f;
  y = y * z + x;
  y = y + 1.0f;
  int n = (int)fx;
  y = y * __uint_as_float((uint32_t)(n + 127) << 23);
  return y;
}

// XLA GenerateVF32Log replica = Pommier/Eigen3.3 log_ps (Horner + tail:
// y+=e*q1; y-=0.5*z; x+=y; x+=e*q2). NO contraction.
__device__ static float xla_log(float x_in) {
#pragma clang fp contract(off)
  float xv = fmaxf(x_in, 1.17549435e-38f);      // min_norm_pos clamp
  uint32_t bits = __float_as_uint(xv);
  float e = (float)((int)(bits >> 23) - 126);
  float x = __uint_as_float((bits & 0x007FFFFFu) | 0x3F000000u);  // [0.5,1)
  bool m = (x < 0.707106781186547524f);
  float tmp = m ? x : 0.0f;
  x = x - 1.0f;
  e = e - (m ? 1.0f : 0.0f);
  x = x + tmp;
  float z = x * x;
  float y = 7.0376836292e-2f;
  y = y * x + -1.1514610310e-1f;
  y = y * x + 1.1676998740e-1f;
  y = y * x + -1.2420140846e-1f;
  y = y * x + 1.4249322787e-1f;
  y = y * x + -1.6668057665e-1f;
  y = y * x + 2.0000714765e-1f;
  y = y * x + -2.4999993993e-1f;
  y = y * x + 3.3333331174e-1f;
  y = y * x;
  y = y * z;
  float t1 = e * -2.12194440e-4f;
  y = y + t1;
  float t2 = z * 0.5f;
  y = y - t2;
  x = x + y;
  float t3 = e * 0.693359375f;
  x = x + t3;
  return x;
}

// ---------------- kernels ----------------

__global__ void k_sentinel(float* out, float d) {
  out[0] = d;
}

// v0 one-hot (B,C,V) -> idx (B,V) u8
__global__ __launch_bounds__(256) void k_idx(const float* __restrict__ v0,
                                             uint8_t* __restrict__ idx) {
  int t = blockIdx.x * 256 + threadIdx.x;          // b*V + v
  int b = t >> 9, v = t & 511;
  const float* p = v0 + (size_t)b * (C_DIM * V_DIM) + v;
  int cf = 0;
#pragma unroll
  for (int c = 0; c < C_DIM; ++c)
    if (p[c * V_DIM] > 0.5f) cf = c;
  idx[t] = (uint8_t)cf;
}

// W (c,h,v) -> Wt (c,v,h)
__global__ __launch_bounds__(256) void k_wt(const float* __restrict__ W,
                                            float* __restrict__ Wt) {
  int t = blockIdx.x * 256 + threadIdx.x;          // (c, v, h)
  int h = t & 255; int rest = t >> 8; int v = rest & 511; int c = rest >> 9;
  Wt[t] = W[((size_t)c * H_DIM + h) * V_DIM + v];
}

// h = bernoulli(sigmoid(kc-slab-folded k-ascending sum + c1))
// In-LDS compaction: ballot counting-sort -> soff[512] = byte offsets
// of selected k ascending; jb[s] = panel boundaries (lower_bound s*KC).
// Accumulation order bit-identical to round 6.
__global__ __launch_bounds__(256) void k_sample_h(
    const float* __restrict__ Wt, const float* __restrict__ c1,
    const uint8_t* __restrict__ idx,
    float* __restrict__ out_h, uint32_t* __restrict__ out_mask,
    uint32_t key0, uint32_t key1) {
  __shared__ uint8_t  sidx[V_DIM];
  __shared__ uint32_t soff[V_DIM];     // (c*512+v)*1024 byte offsets, k asc
  __shared__ uint16_t cnt[8][5];       // per 64-lane segment, per class
  __shared__ uint16_t base[8][5];      // global start position
  __shared__ uint16_t jb[10];          // panel boundaries in j-space
  int b = blockIdx.x;
  int t = threadIdx.x;
  if (t < 128)
    ((uint32_t*)sidx)[t] = ((const uint32_t*)(idx + (size_t)b * V_DIM))[t];
  __syncthreads();

  int lane = t & 63, wv = t >> 6;
  // pass 0: v = t (segments 0..3); pass 1: v = t+256 (segments 4..7)
  int v0 = t,       c0 = sidx[v0];
  int v1 = t + 256, c1i = sidx[v1];
  int rank0, rank1;
  {
    unsigned long long bal[5];
#pragma unroll
    for (int cc = 0; cc < 5; ++cc) bal[cc] = __ballot(c0 == cc);
    if (lane == 0) {
#pragma unroll
      for (int cc = 0; cc < 5; ++cc) cnt[wv][cc] = (uint16_t)__popcll(bal[cc]);
    }
    rank0 = (int)__popcll(bal[c0] & ((1ull << lane) - 1ull));
  }
  {
    unsigned long long bal[5];
#pragma unroll
    for (int cc = 0; cc < 5; ++cc) bal[cc] = __ballot(c1i == cc);
    if (lane == 0) {
#pragma unroll
      for (int cc = 0; cc < 5; ++cc) cnt[4 + wv][cc] = (uint16_t)__popcll(bal[cc]);
    }
    rank1 = (int)__popcll(bal[c1i] & ((1ull << lane) - 1ull));
  }
  __syncthreads();
  if (t == 0) {
    int pos = 0;
    for (int cc = 0; cc < 5; ++cc)
      for (int g = 0; g < 8; ++g) { base[g][cc] = (uint16_t)pos; pos += cnt[g][cc]; }
  }
  __syncthreads();
  soff[base[wv][c0] + rank0]       = (uint32_t)(c0 * V_DIM + v0) << 10;   // k*1024B
  soff[base[4 + wv][c1i] + rank1]  = (uint32_t)(c1i * V_DIM + v1) << 10;
  __syncthreads();
  if (t < 10) {
    uint32_t target = (uint32_t)(t * KC) << 10;
    int lo = 0, hi = V_DIM;
    while (lo < hi) { int mid = (lo + hi) >> 1;
      if (soff[mid] < target) lo = mid + 1; else hi = mid; }
    jb[t] = (uint16_t)lo;
  }
  __syncthreads();

  // main accumulation: h = t
  const char* Wh = (const char*)Wt + (size_t)t * 4;
  float total = 0.0f;
  for (int s = 0; s < 9; ++s) {
    int j = jb[s], jend = jb[s + 1];
    float psum = 0.0f;
    for (; j + 4 <= jend; j += 4) {
      float w0 = *(const float*)(Wh + soff[j]);
      float w1 = *(const float*)(Wh + soff[j + 1]);
      float w2 = *(const float*)(Wh + soff[j + 2]);
      float w3 = *(const float*)(Wh + soff[j + 3]);
      psum += w0; psum += w1; psum += w2; psum += w3;
    }
    for (; j < jend; ++j) psum += *(const float*)(Wh + soff[j]);
    total += psum;
  }

  float tt = total + c1[t];
  float p = 1.0f / (1.0f + xla_exp(-tt));   // IEEE div, logistic exp form

  uint32_t i = (uint32_t)(b * H_DIM + t);
  float u = bits_to_unit_float(rng_bits(key0, key1, i));
  bool hb = (u < p);
  if (out_h) out_h[(size_t)b * H_DIM + t] = hb ? 1.0f : 0.0f;

  unsigned long long m = __ballot(hb);
  if ((t & 63) == 0) {
    out_mask[(size_t)b * 8 + wv * 2 + 0] = (uint32_t)(m & 0xFFFFFFFFull);
    out_mask[(size_t)b * 8 + wv * 2 + 1] = (uint32_t)(m >> 32);
  }
}

// v = categorical over c of (sum_h W[c,h,v]*hbit + b2 + gumbel); 8 b's/block
__global__ __launch_bounds__(512) void k_sample_v(
    const float* __restrict__ W, const float* __restrict__ b2,
    const uint32_t* __restrict__ mask, uint8_t* __restrict__ idx_out,
    uint32_t key0, uint32_t key1) {
  __shared__ uint32_t sm[8][8];
  int v = threadIdx.x;
  int b0 = blockIdx.x * 8;
  if (threadIdx.x < 64)
    sm[threadIdx.x >> 3][threadIdx.x & 7] = mask[(size_t)b0 * 8 + threadIdx.x];
  __syncthreads();

  float best[8];
  int bc[8];
#pragma unroll
  for (int g = 0; g < 8; ++g) { best[g] = 0.0f; bc[g] = 0; }

  for (int c = 0; c < C_DIM; ++c) {
    float acc[8] = {0.f,0.f,0.f,0.f,0.f,0.f,0.f,0.f};
    const float* Wc = W + (size_t)c * (H_DIM * V_DIM) + v;
    for (int word = 0; word < 8; ++word) {
      uint32_t mw[8];
#pragma unroll
      for (int g = 0; g < 8; ++g) mw[g] = sm[g][word];
      for (int bit = 0; bit < 32; ++bit) {
        float w = Wc[(size_t)(word * 32 + bit) * V_DIM];
#pragma unroll
        for (int g = 0; g < 8; ++g)
          acc[g] += ((mw[g] >> bit) & 1u) ? w : 0.0f;  // exact skip/add
      }
    }
    float bias = b2[(size_t)c * V_DIM + v];
#pragma unroll
    for (int g = 0; g < 8; ++g) {
      float logit = acc[g] + bias;
      uint32_t i = (uint32_t)((b0 + g) * (C_DIM * V_DIM) + c * V_DIM + v);
      float uf = bits_to_unit_float(rng_bits(key0, key1, i));
      if (uf == 0.0f) uf = 1.17549435e-38f;            // u + tiny semantics
      float gum = -xla_log(-xla_log(uf));
      float z = gum + logit;
      if (c == 0 || z > best[g]) { best[g] = z; bc[g] = c; }
    }
  }
#pragma unroll
  for (int g = 0; g < 8; ++g)
    idx_out[(size_t)(b0 + g) * V_DIM + v] = (uint8_t)bc[g];
}

// idx -> one-hot f32 (B,C,V)
__global__ __launch_bounds__(256) void k_onehot(const uint8_t* __restrict__ idx,
                                                float* __restrict__ out) {
  int t = blockIdx.x * 256 + threadIdx.x;     // b*C*V + c*V + v
  int v = t & 511; int rest = t >> 9; int c = rest % C_DIM; int b = rest / C_DIM;
  out[t] = (idx[(size_t)b * V_DIM + v] == c) ? 1.0f : 0.0f;
}

// ---------------- launch ----------------

extern "C" void kernel_launch(void* const* d_in, const int* in_sizes, int n_in,
                              void* d_out, int out_size, void* d_ws, size_t ws_size,
                              hipStream_t stream) {
  float* out = (float*)d_out;

  // ---- structural sentinels (verified silent in rounds 5-6) ----
  const size_t WS_NEED = 2621440ull + 8388608ull + 524288ull;  // 11,534,336 B
  float D = 0.0f;
  if (n_in < 4)                       D = 910.0f + (float)n_in;
  else if (in_sizes[0] != 41943040)   D = 920.0f;
  else if (in_sizes[1] != 655360)     D = 921.0f;
  else if (in_sizes[2] != 2560)       D = 922.0f;
  else if (in_sizes[3] != 256)        D = 923.0f;
  else if (out_size != 50331648)      D = 930.0f + (float)out_size * 1e-6f;
  else if (ws_size < WS_NEED)         D = 100.0f + (float)(ws_size >> 20);
  if (D != 0.0f) {
    hipLaunchKernelGGL(k_sentinel, dim3(1), dim3(1), 0, stream, out, D);
    return;
  }

  const float* v0 = (const float*)d_in[0];
  const float* W  = (const float*)d_in[1];
  const float* b2 = (const float*)d_in[2];   // (C,V)
  const float* c1 = (const float*)d_in[3];   // (H)

  float* out_v  = out;                                         // B*C*V
  float* out_h  = out + (size_t)B_DIM * C_DIM * V_DIM;         // B*H (final h)
  float* out_h0 = out_h + (size_t)B_DIM * H_DIM;               // B*H (h|v0)

  char* ws = (char*)d_ws;
  float*    Wt   = (float*)(ws);                    // 2,621,440 B
  uint8_t*  idx  = (uint8_t*)(ws + 2621440);        // 8,388,608 B
  uint32_t* mask = (uint32_t*)(ws + 11010048);      //   524,288 B

  // partitionable (fold-like) split of key(42) into 5 subkeys
  uint32_t keys[5][2];
  for (int i = 0; i < 5; ++i) {
    TFOut r = tf2x32(0u, 42u, 0u, (uint32_t)i);
    keys[i][0] = r.a; keys[i][1] = r.b;
  }

  hipLaunchKernelGGL(k_wt,  dim3(2560),  dim3(256), 0, stream, W, Wt);
  hipLaunchKernelGGL(k_idx, dim3(32768), dim3(256), 0, stream, v0, idx);

  // h0 = sample_h(keys[0], v0) -> h_given_v0 output + mask
  hipLaunchKernelGGL(k_sample_h, dim3(B_DIM), dim3(256), 0, stream,
                     Wt, c1, idx, out_h0, mask, keys[0][0], keys[0][1]);
  // iter 0: v = sample_v(keys[1], h0); h1 = sample_h(keys[2], v)
  hipLaunchKernelGGL(k_sample_v, dim3(B_DIM / 8), dim3(512), 0, stream,
                     W, b2, mask, idx, keys[1][0], keys[1][1]);
  hipLaunchKernelGGL(k_sample_h, dim3(B_DIM), dim3(256), 0, stream,
                     Wt, c1, idx, (float*)nullptr, mask, keys[2][0], keys[2][1]);
  // iter 1: v = sample_v(keys[3], h1); h2 = sample_h(keys[4], v)
  hipLaunchKernelGGL(k_sample_v, dim3(B_DIM / 8), dim3(512), 0, stream,
                     W, b2, mask, idx, keys[3][0], keys[3][1]);
  hipLaunchKernelGGL(k_sample_h, dim3(B_DIM), dim3(256), 0, stream,
                     Wt, c1, idx, out_h, mask, keys[4][0], keys[4][1]);
  // final v one-hot output
  hipLaunchKernelGGL(k_onehot, dim3(163840), dim3(256), 0, stream, idx, out_v);
}